// Round 12
// baseline (572.608 us; speedup 1.0000x reference)
//
#include <hip/hip_runtime.h>
#include <hip/hip_bf16.h>

#define N_NODES 100000
#define N_EDGES 320000
#define HID 256
#define NE 128
#define NLAYERS 3

typedef __attribute__((ext_vector_type(8))) short short8;
typedef __attribute__((ext_vector_type(4))) float f32x4;

__device__ inline float bfbits2f(unsigned int b) { return __uint_as_float(b << 16); }

__device__ inline unsigned int pack_bf2(float lo, float hi) {
    __hip_bfloat16 l = __float2bfloat16(lo), h = __float2bfloat16(hi);
    return (unsigned int)*(unsigned short*)&l |
           ((unsigned int)*(unsigned short*)&h << 16);
}

// ---------------------------------------------------------------------------
// Weight prep: fp32 -> bf16, transposed to [n][k].  Also zeroes deg/total.
// ---------------------------------------------------------------------------
__global__ __launch_bounds__(256) void k_prep(
    const float* __restrict__ Wl, const float* __restrict__ Wr,
    const float* __restrict__ W0,
    __hip_bfloat16* __restrict__ Wt, __hip_bfloat16* __restrict__ Wh,
    int* __restrict__ deg, int* __restrict__ total)
{
    int t = blockIdx.x * 256 + threadIdx.x;
    const int total_sage = 3 * 256 * 512;
    if (t < total_sage) {
        int l = t >> 17;
        int rem = t & 131071;
        int n = rem >> 9;
        int k = rem & 511;
        const float* Wsrc = (k < 256) ? (Wl + (size_t)l * 65536)
                                      : (Wr + (size_t)l * 65536);
        Wt[t] = __float2bfloat16(Wsrc[(k & 255) * 256 + n]);
    } else {
        int u = t - total_sage;
        if (u < 65536) {
            int n = u >> 8, k = u & 255;
            Wh[u] = __float2bfloat16(W0[k * 256 + n]);
        }
    }
    if (t < N_NODES) deg[t] = 0;
    if (t == 0) *total = 0;
}

// ---------------------------------------------------------------------------
// Init (vectorized): 32 thr/node, 8B uint2 stores.  Tail ranges: output tail
// and the edge histogram (deg zeroed by k_prep earlier in stream order).
// ---------------------------------------------------------------------------
__global__ __launch_bounds__(256) void k_init(
    const float* __restrict__ node_attr,
    const float* __restrict__ node_emb,
    const float* __restrict__ net_W, const float* __restrict__ net_b,
    const float* __restrict__ dev_W, const float* __restrict__ dev_b,
    const float* __restrict__ pin_emb,
    const int*   __restrict__ node_type,
    const float* __restrict__ y, const float* __restrict__ b1,
    const int*   __restrict__ edge_index, int* __restrict__ deg,
    float* __restrict__ out,
    __hip_bfloat16* __restrict__ x)
{
    int t = blockIdx.x * 256 + threadIdx.x;
    if (t < N_NODES * 32) {
        int n  = t >> 5;
        int c4 = (t & 31) * 4;
        int ty = node_type[n];
        float4 e = *(const float4*)(node_emb + ty * NE + c4);
        float4 a;
        if (ty == 0 || ty == 1) {
            const float* W = (ty == 0) ? net_W : dev_W;
            const float* b = (ty == 0) ? net_b : dev_b;
            a = *(const float4*)(b + c4);
            const float* ar = node_attr + (size_t)n * 17;
            #pragma unroll
            for (int k = 0; k < 17; ++k) {
                float av = ar[k];
                float4 wv = *(const float4*)(W + k * NE + c4);
                a.x += av * wv.x; a.y += av * wv.y;
                a.z += av * wv.z; a.w += av * wv.w;
            }
        } else if (ty == 2) {
            int idx = (int)node_attr[(size_t)n * 17];
            a = *(const float4*)(pin_emb + idx * NE + c4);
        } else {
            a.x = a.y = a.z = a.w = 0.0f;
        }
        uint2 ev = {pack_bf2(e.x, e.y), pack_bf2(e.z, e.w)};
        uint2 av = {pack_bf2(a.x, a.y), pack_bf2(a.z, a.w)};
        *(uint2*)((char*)x + (size_t)n * 512 + c4 * 2)       = ev;
        *(uint2*)((char*)x + (size_t)n * 512 + 256 + c4 * 2) = av;
    } else if (t < N_NODES * 33) {
        int n = t - N_NODES * 32;
        float y0 = y[(size_t)n * 2 + 0];
        float y1 = y[(size_t)n * 2 + 1];
        out[n] = b1[0];
        out[N_NODES + n] = (float)(int)y1;
        out[2 * N_NODES + 2 * n + 0] = y0;
        out[2 * N_NODES + 2 * n + 1] = y1;
    } else {
        int e = t - N_NODES * 33;
        if (e < N_EDGES) atomicAdd(&deg[edge_index[N_EDGES + e]], 1);
    }
}

// ---------------------------------------------------------------------------
// CSR build: scan-free chunk allocation -> fill
// ---------------------------------------------------------------------------
__global__ __launch_bounds__(256) void k_alloc(
    const int* __restrict__ deg, int* __restrict__ off,
    int* __restrict__ cursor, int* __restrict__ total)
{
    int n = blockIdx.x * 256 + threadIdx.x;
    int lane = threadIdx.x & 63;
    int d = (n < N_NODES) ? deg[n] : 0;
    int incl = d;
    #pragma unroll
    for (int o = 1; o < 64; o <<= 1) {
        int v = __shfl_up(incl, o, 64);
        if (lane >= o) incl += v;
    }
    int wtot = __shfl(incl, 63, 64);
    int base = 0;
    if (lane == 63) base = atomicAdd(total, wtot);
    base = __shfl(base, 63, 64);
    if (n < N_NODES) {
        int o = base + incl - d;
        off[n] = o;
        cursor[n] = o;
    }
}

__global__ __launch_bounds__(256) void k_fill(
    const int* __restrict__ edge_index, int* __restrict__ cursor,
    int* __restrict__ slots)
{
    int e = blockIdx.x * 256 + threadIdx.x;
    if (e >= N_EDGES) return;
    int s = edge_index[e];
    int d = edge_index[N_EDGES + e];
    int slot = atomicAdd(&cursor[d], 1);
    slots[slot] = s;
}

// ---------------------------------------------------------------------------
// Gather-mean: 4 nodes per wave, 16 lanes x 32B per node, fp32 accumulate.
// ---------------------------------------------------------------------------
__global__ __launch_bounds__(256) void k_aggregate(
    const __hip_bfloat16* __restrict__ x,
    const int* __restrict__ off, const int* __restrict__ deg,
    const int* __restrict__ slots,
    __hip_bfloat16* __restrict__ agg)
{
    int g = blockIdx.x * 256 + threadIdx.x;
    int wid = g >> 6;
    int lane = g & 63;
    int sub = lane >> 4;
    int l16 = lane & 15;
    int n = wid * 4 + sub;
    bool active = n < N_NODES;
    int o = 0, d = 0;
    if (active) { o = off[n]; d = deg[n]; }
    float acc[16];
    #pragma unroll
    for (int i = 0; i < 16; ++i) acc[i] = 0.0f;
    for (int p = 0; p < d; ++p) {
        int src = slots[o + p];
        const char* rp = (const char*)x + (size_t)src * 512 + l16 * 32;
        uint4 v0 = *(const uint4*)rp;
        uint4 v1 = *(const uint4*)(rp + 16);
        const unsigned int u[8] = {v0.x, v0.y, v0.z, v0.w, v1.x, v1.y, v1.z, v1.w};
        #pragma unroll
        for (int i = 0; i < 8; ++i) {
            acc[2 * i + 0] += bfbits2f(u[i] & 0xffffu);
            acc[2 * i + 1] += __uint_as_float(u[i] & 0xffff0000u);
        }
    }
    if (active) {
        float rs = 1.0f / fmaxf((float)d, 1.0f);
        unsigned int w[8];
        #pragma unroll
        for (int i = 0; i < 8; ++i)
            w[i] = pack_bf2(acc[2 * i + 0] * rs, acc[2 * i + 1] * rs);
        uint4 o0 = {w[0], w[1], w[2], w[3]};
        uint4 o1 = {w[4], w[5], w[6], w[7]};
        char* op = (char*)agg + (size_t)n * 512 + l16 * 32;
        *(uint4*)op = o0;
        *(uint4*)(op + 16) = o1;
    }
}

// ---------------------------------------------------------------------------
// MFMA layer, flat-TLP: NO LDS staging, NO barriers.
// Block 256 thr = 4 waves = one 64-row group; wave w owns cols w*64..+63.
// A-frags loaded directly from global (16B/lane; 4 waves share the same
// 32KB of A rows -> L1/L2 hits); B-frags from the L2-hot 256KB Wt panel.
// 16 (SAGE) / 8 (HEAD) fully-unrolled K-steps x 16 MFMA; latency hidden by
// wave-level TLP (the thing every barrier-locked LDS schedule lacked:
// R5/R7/R10/R11 all ~52us regardless of buffering/barrier count).
// Epilogue: wave-private LDS transpose (stride-68 shorts: ds_write_b16
// conflict-free), lgkmcnt-only sync, coalesced 16B stores.
// SAGE: Out = relu([Agg|X] @ Wt^T + bias)   (K=512)
// HEAD: Pred += relu(X @ Wh^T + bias) . W1  (K=256, atomicAdd partials)
// ---------------------------------------------------------------------------
template <bool SAGE>
__global__ __launch_bounds__(256, 4) void k_mfma(
    const __hip_bfloat16* __restrict__ Agg,
    const __hip_bfloat16* __restrict__ X,
    const __hip_bfloat16* __restrict__ Wt,
    const float* __restrict__ bias,
    const float* __restrict__ W1,
    __hip_bfloat16* __restrict__ Out,
    float* __restrict__ Pred)
{
    __shared__ short eps[4][16 * 68 + 8];   // per-wave transpose scratch

    const int tid  = threadIdx.x;
    const int w    = tid >> 6, lane = tid & 63;
    const int l15  = lane & 15, lg = lane >> 4;
    const int row0 = blockIdx.x * 64;
    const int col0 = w * 64;
    const int KTB    = (SAGE ? 512 : 256) * 2;   // bytes per Wt row
    const int nsteps = SAGE ? 16 : 8;

    f32x4 acc[4][4];
    #pragma unroll
    for (int i = 0; i < 4; ++i)
        #pragma unroll
        for (int n = 0; n < 4; ++n) acc[i][n] = (f32x4)0.0f;

    // per-lane A row byte offsets (clamped; clamp rows discarded at store)
    size_t roff[4];
    #pragma unroll
    for (int i = 0; i < 4; ++i) {
        int r = row0 + i * 16 + l15;
        if (r >= N_NODES) r = N_NODES - 1;
        roff[i] = (size_t)r * 512;
    }
    // per-lane B row base (col of Out = row of Wt)
    const char* brow[4];
    #pragma unroll
    for (int n = 0; n < 4; ++n)
        brow[n] = (const char*)Wt + (size_t)(col0 + n * 16 + l15) * KTB;

    #pragma unroll
    for (int ks = 0; ks < nsteps; ++ks) {
        const char* abase = (SAGE && ks < 8) ? (const char*)Agg : (const char*)X;
        const int kb = (ks & 7) * 64 + lg * 16;
        short8 a[4], b[4];
        #pragma unroll
        for (int i = 0; i < 4; ++i)
            a[i] = *(const short8*)(abase + roff[i] + kb);
        #pragma unroll
        for (int n = 0; n < 4; ++n)
            b[n] = *(const short8*)(brow[n] + ks * 64 + lg * 16);
        #pragma unroll
        for (int i = 0; i < 4; ++i)
            #pragma unroll
            for (int n = 0; n < 4; ++n)
                acc[i][n] = __builtin_amdgcn_mfma_f32_16x16x32_bf16(
                    a[i], b[n], acc[i][n], 0, 0, 0);
    }

    if (SAGE) {
        short* ep = eps[w];
        #pragma unroll
        for (int i = 0; i < 4; ++i) {
            // scatter-write frag i (16 rows x 64 cols) into stride-68 scratch
            #pragma unroll
            for (int n = 0; n < 4; ++n) {
                float bv = bias[col0 + n * 16 + l15];
                #pragma unroll
                for (int r = 0; r < 4; ++r) {
                    __hip_bfloat16 hv =
                        __float2bfloat16(fmaxf(acc[i][n][r] + bv, 0.0f));
                    ep[(lg * 4 + r) * 68 + n * 16 + l15] = *(short*)&hv;
                }
            }
            asm volatile("s_waitcnt lgkmcnt(0)" ::: "memory");
            __builtin_amdgcn_sched_barrier(0);
            // coalesced read + 16B global stores: 2 x (8 rows x 8 chunks)
            #pragma unroll
            for (int q = 0; q < 2; ++q) {
                int rl = q * 8 + (lane >> 3);
                int cc = lane & 7;
                short8 v = *(const short8*)&ep[rl * 68 + cc * 8];
                int grow = row0 + i * 16 + rl;
                if (grow < N_NODES)
                    *(short8*)((char*)Out + (size_t)grow * 512 + col0 * 2 + cc * 16) = v;
            }
            asm volatile("s_waitcnt lgkmcnt(0)" ::: "memory");
            __builtin_amdgcn_sched_barrier(0);
        }
    } else {
        #pragma unroll
        for (int i = 0; i < 4; ++i) {
            float p[4];
            #pragma unroll
            for (int r = 0; r < 4; ++r) p[r] = 0.0f;
            #pragma unroll
            for (int n = 0; n < 4; ++n) {
                int cg = col0 + n * 16 + l15;
                float bv = bias[cg];
                float wv = W1[cg];
                #pragma unroll
                for (int r = 0; r < 4; ++r)
                    p[r] += fmaxf(acc[i][n][r] + bv, 0.0f) * wv;
            }
            #pragma unroll
            for (int r = 0; r < 4; ++r) {
                float s = p[r];
                #pragma unroll
                for (int m = 1; m < 16; m <<= 1) s += __shfl_xor(s, m, 64);
                if (l15 == 0) {
                    int grow = row0 + i * 16 + lg * 4 + r;
                    if (grow < N_NODES) atomicAdd(&Pred[grow], s);
                }
            }
        }
    }
}

extern "C" void kernel_launch(void* const* d_in, const int* in_sizes, int n_in,
                              void* d_out, int out_size, void* d_ws, size_t ws_size,
                              hipStream_t stream) {
    const float* node_attr = (const float*)d_in[0];
    const float* y         = (const float*)d_in[1];
    const float* node_emb  = (const float*)d_in[2];
    const float* net_W     = (const float*)d_in[4];
    const float* net_b     = (const float*)d_in[5];
    const float* dev_W     = (const float*)d_in[6];
    const float* dev_b     = (const float*)d_in[7];
    const float* pin_emb   = (const float*)d_in[8];
    const float* sage_Wl   = (const float*)d_in[9];
    const float* sage_bl   = (const float*)d_in[10];
    const float* sage_Wr   = (const float*)d_in[11];
    const float* head_W0   = (const float*)d_in[12];
    const float* head_b0   = (const float*)d_in[13];
    const float* head_W1   = (const float*)d_in[14];
    const float* head_b1   = (const float*)d_in[15];
    const int*   node_type = (const int*)d_in[16];
    const int*   edge_idx  = (const int*)d_in[18];
    float* out = (float*)d_out;

    const size_t xelems = (size_t)N_NODES * HID;
    char* p = (char*)d_ws;
    __hip_bfloat16* x0  = (__hip_bfloat16*)p;  p += xelems * 2;
    __hip_bfloat16* x1  = (__hip_bfloat16*)p;  p += xelems * 2;
    __hip_bfloat16* agg = (__hip_bfloat16*)p;  p += xelems * 2;
    __hip_bfloat16* Wt  = (__hip_bfloat16*)p;  p += (size_t)3 * 256 * 512 * 2;
    __hip_bfloat16* Wh  = (__hip_bfloat16*)p;  p += (size_t)256 * 256 * 2;
    int* deg    = (int*)p; p += N_NODES * 4;
    int* off    = (int*)p; p += N_NODES * 4;
    int* cursor = (int*)p; p += N_NODES * 4;
    int* slots  = (int*)p; p += N_EDGES * 4;
    int* total  = (int*)p; p += 16;

    k_prep<<<(3 * 131072 + 65536 + 255) / 256, 256, 0, stream>>>(
        sage_Wl, sage_Wr, head_W0, Wt, Wh, deg, total);
    k_init<<<(N_NODES * 33 + N_EDGES + 255) / 256, 256, 0, stream>>>(
        node_attr, node_emb, net_W, net_b, dev_W, dev_b, pin_emb, node_type,
        y, head_b1, edge_idx, deg, out, x0);
    k_alloc<<<(N_NODES + 255) / 256, 256, 0, stream>>>(deg, off, cursor, total);
    k_fill<<<(N_EDGES + 255) / 256, 256, 0, stream>>>(edge_idx, cursor, slots);

    const int gemm_grid = (N_NODES + 63) / 64;   // 1563 blocks, 4 waves each
    __hip_bfloat16* xcur = x0;
    __hip_bfloat16* xalt = x1;
    for (int l = 0; l < NLAYERS; ++l) {
        k_aggregate<<<(N_NODES / 4 * 64 + 255) / 256, 256, 0, stream>>>(
            xcur, off, deg, slots, agg);
        k_mfma<true><<<gemm_grid, 256, 0, stream>>>(
            agg, xcur, Wt + (size_t)l * 131072,
            sage_bl + (size_t)l * HID, nullptr, xalt, nullptr);
        __hip_bfloat16* t = xcur; xcur = xalt; xalt = t;
    }
    k_mfma<false><<<gemm_grid, 256, 0, stream>>>(
        xcur, xcur, Wh, head_b0, head_W1, nullptr, out);
}

// Round 13
// 361.419 us; speedup vs baseline: 1.5843x; 1.5843x over previous
//
#include <hip/hip_runtime.h>
#include <hip/hip_bf16.h>

#define N_NODES 100000
#define N_EDGES 320000
#define HID 256
#define NE 128
#define NLAYERS 3

typedef __attribute__((ext_vector_type(8))) short short8;
typedef __attribute__((ext_vector_type(4))) float f32x4;

__device__ inline float bfbits2f(unsigned int b) { return __uint_as_float(b << 16); }

__device__ inline unsigned int pack_bf2(float lo, float hi) {
    __hip_bfloat16 l = __float2bfloat16(lo), h = __float2bfloat16(hi);
    return (unsigned int)*(unsigned short*)&l |
           ((unsigned int)*(unsigned short*)&h << 16);
}

// ---------------------------------------------------------------------------
// Weight prep: fp32 -> bf16, transposed to [n][k].  Also zeroes deg/total.
// ---------------------------------------------------------------------------
__global__ __launch_bounds__(256) void k_prep(
    const float* __restrict__ Wl, const float* __restrict__ Wr,
    const float* __restrict__ W0,
    __hip_bfloat16* __restrict__ Wt, __hip_bfloat16* __restrict__ Wh,
    int* __restrict__ deg, int* __restrict__ total)
{
    int t = blockIdx.x * 256 + threadIdx.x;
    const int total_sage = 3 * 256 * 512;
    if (t < total_sage) {
        int l = t >> 17;
        int rem = t & 131071;
        int n = rem >> 9;
        int k = rem & 511;
        const float* Wsrc = (k < 256) ? (Wl + (size_t)l * 65536)
                                      : (Wr + (size_t)l * 65536);
        Wt[t] = __float2bfloat16(Wsrc[(k & 255) * 256 + n]);
    } else {
        int u = t - total_sage;
        if (u < 65536) {
            int n = u >> 8, k = u & 255;
            Wh[u] = __float2bfloat16(W0[k * 256 + n]);
        }
    }
    if (t < N_NODES) deg[t] = 0;
    if (t == 0) *total = 0;
}

// ---------------------------------------------------------------------------
// Init (vectorized): 32 thr/node, 8B uint2 stores.  Tail ranges: output tail
// and the edge histogram (deg zeroed by k_prep earlier in stream order).
// ---------------------------------------------------------------------------
__global__ __launch_bounds__(256) void k_init(
    const float* __restrict__ node_attr,
    const float* __restrict__ node_emb,
    const float* __restrict__ net_W, const float* __restrict__ net_b,
    const float* __restrict__ dev_W, const float* __restrict__ dev_b,
    const float* __restrict__ pin_emb,
    const int*   __restrict__ node_type,
    const float* __restrict__ y, const float* __restrict__ b1,
    const int*   __restrict__ edge_index, int* __restrict__ deg,
    float* __restrict__ out,
    __hip_bfloat16* __restrict__ x)
{
    int t = blockIdx.x * 256 + threadIdx.x;
    if (t < N_NODES * 32) {
        int n  = t >> 5;
        int c4 = (t & 31) * 4;
        int ty = node_type[n];
        float4 e = *(const float4*)(node_emb + ty * NE + c4);
        float4 a;
        if (ty == 0 || ty == 1) {
            const float* W = (ty == 0) ? net_W : dev_W;
            const float* b = (ty == 0) ? net_b : dev_b;
            a = *(const float4*)(b + c4);
            const float* ar = node_attr + (size_t)n * 17;
            #pragma unroll
            for (int k = 0; k < 17; ++k) {
                float av = ar[k];
                float4 wv = *(const float4*)(W + k * NE + c4);
                a.x += av * wv.x; a.y += av * wv.y;
                a.z += av * wv.z; a.w += av * wv.w;
            }
        } else if (ty == 2) {
            int idx = (int)node_attr[(size_t)n * 17];
            a = *(const float4*)(pin_emb + idx * NE + c4);
        } else {
            a.x = a.y = a.z = a.w = 0.0f;
        }
        uint2 ev = {pack_bf2(e.x, e.y), pack_bf2(e.z, e.w)};
        uint2 av = {pack_bf2(a.x, a.y), pack_bf2(a.z, a.w)};
        *(uint2*)((char*)x + (size_t)n * 512 + c4 * 2)       = ev;
        *(uint2*)((char*)x + (size_t)n * 512 + 256 + c4 * 2) = av;
    } else if (t < N_NODES * 33) {
        int n = t - N_NODES * 32;
        float y0 = y[(size_t)n * 2 + 0];
        float y1 = y[(size_t)n * 2 + 1];
        out[n] = b1[0];
        out[N_NODES + n] = (float)(int)y1;
        out[2 * N_NODES + 2 * n + 0] = y0;
        out[2 * N_NODES + 2 * n + 1] = y1;
    } else {
        int e = t - N_NODES * 33;
        if (e < N_EDGES) atomicAdd(&deg[edge_index[N_EDGES + e]], 1);
    }
}

// ---------------------------------------------------------------------------
// CSR build: scan-free chunk allocation -> fill
// ---------------------------------------------------------------------------
__global__ __launch_bounds__(256) void k_alloc(
    const int* __restrict__ deg, int* __restrict__ off,
    int* __restrict__ cursor, int* __restrict__ total)
{
    int n = blockIdx.x * 256 + threadIdx.x;
    int lane = threadIdx.x & 63;
    int d = (n < N_NODES) ? deg[n] : 0;
    int incl = d;
    #pragma unroll
    for (int o = 1; o < 64; o <<= 1) {
        int v = __shfl_up(incl, o, 64);
        if (lane >= o) incl += v;
    }
    int wtot = __shfl(incl, 63, 64);
    int base = 0;
    if (lane == 63) base = atomicAdd(total, wtot);
    base = __shfl(base, 63, 64);
    if (n < N_NODES) {
        int o = base + incl - d;
        off[n] = o;
        cursor[n] = o;
    }
}

__global__ __launch_bounds__(256) void k_fill(
    const int* __restrict__ edge_index, int* __restrict__ cursor,
    int* __restrict__ slots)
{
    int e = blockIdx.x * 256 + threadIdx.x;
    if (e >= N_EDGES) return;
    int s = edge_index[e];
    int d = edge_index[N_EDGES + e];
    int slot = atomicAdd(&cursor[d], 1);
    slots[slot] = s;
}

// ---------------------------------------------------------------------------
// Gather-mean: 4 nodes per wave, 16 lanes x 32B per node, fp32 accumulate.
// ---------------------------------------------------------------------------
__global__ __launch_bounds__(256) void k_aggregate(
    const __hip_bfloat16* __restrict__ x,
    const int* __restrict__ off, const int* __restrict__ deg,
    const int* __restrict__ slots,
    __hip_bfloat16* __restrict__ agg)
{
    int g = blockIdx.x * 256 + threadIdx.x;
    int wid = g >> 6;
    int lane = g & 63;
    int sub = lane >> 4;
    int l16 = lane & 15;
    int n = wid * 4 + sub;
    bool active = n < N_NODES;
    int o = 0, d = 0;
    if (active) { o = off[n]; d = deg[n]; }
    float acc[16];
    #pragma unroll
    for (int i = 0; i < 16; ++i) acc[i] = 0.0f;
    for (int p = 0; p < d; ++p) {
        int src = slots[o + p];
        const char* rp = (const char*)x + (size_t)src * 512 + l16 * 32;
        uint4 v0 = *(const uint4*)rp;
        uint4 v1 = *(const uint4*)(rp + 16);
        const unsigned int u[8] = {v0.x, v0.y, v0.z, v0.w, v1.x, v1.y, v1.z, v1.w};
        #pragma unroll
        for (int i = 0; i < 8; ++i) {
            acc[2 * i + 0] += bfbits2f(u[i] & 0xffffu);
            acc[2 * i + 1] += __uint_as_float(u[i] & 0xffff0000u);
        }
    }
    if (active) {
        float rs = 1.0f / fmaxf((float)d, 1.0f);
        unsigned int w[8];
        #pragma unroll
        for (int i = 0; i < 8; ++i)
            w[i] = pack_bf2(acc[2 * i + 0] * rs, acc[2 * i + 1] * rs);
        uint4 o0 = {w[0], w[1], w[2], w[3]};
        uint4 o1 = {w[4], w[5], w[6], w[7]};
        char* op = (char*)agg + (size_t)n * 512 + l16 * 32;
        *(uint4*)op = o0;
        *(uint4*)(op + 16) = o1;
    }
}

// ===========================================================================
// Shared GEMM machinery (R10 structure: 3-buffer LDS, single barrier/step,
// counted vmcnt; block 512 thr = 8 waves x 32 cols; tile 128 x 256, BK=64).
// ===========================================================================
#define SAGE_KLOOP(SMEM)                                                      \
    const int tid  = threadIdx.x;                                             \
    const int w    = tid >> 6, lane = tid & 63;                               \
    const int l15  = lane & 15, lg = lane >> 4;                               \
    const int row0 = blockIdx.x * 128;                                        \
    f32x4 acc[8][2];                                                          \
    _Pragma("unroll")                                                         \
    for (int i = 0; i < 8; ++i)                                               \
        _Pragma("unroll")                                                     \
        for (int n = 0; n < 2; ++n) acc[i][n] = (f32x4)0.0f;                  \
    const int srow   = tid >> 3;                                              \
    const int schunk = tid & 7;                                               \
    auto stage = [&](int s) {                                                 \
        const int b = s % 3;                                                  \
        const char* base;                                                     \
        int k0;                                                               \
        if (s < 4) { base = (const char*)Agg; k0 = s * 64; }                  \
        else       { base = (const char*)X;   k0 = (s - 4) * 64; }            \
        _Pragma("unroll")                                                     \
        for (int issue = 0; issue < 2; ++issue) {                             \
            int row  = srow + issue * 64;                                     \
            int grow = row0 + row;                                            \
            if (grow >= N_NODES) grow = N_NODES - 1;                          \
            const char* gp = base + (size_t)grow * 512 + (size_t)k0 * 2       \
                           + ((schunk ^ (row & 7)) << 4);                     \
            const char* lp = SMEM + b * 16384 + issue * 8192 + tid * 16;      \
            __builtin_amdgcn_global_load_lds(                                 \
                (const __attribute__((address_space(1))) void*)gp,            \
                (__attribute__((address_space(3))) void*)lp, 16, 0, 0);       \
        }                                                                     \
    };                                                                        \
    auto loadB = [&](int s, short8 (&bb)[2][2]) {                             \
        _Pragma("unroll")                                                     \
        for (int h = 0; h < 2; ++h)                                           \
            _Pragma("unroll")                                                 \
            for (int n = 0; n < 2; ++n) {                                     \
                int c = w * 32 + n * 16 + l15;                                \
                bb[h][n] = *(const short8*)(Wt + (size_t)c * 512 + s * 64     \
                                            + h * 32 + 8 * lg);               \
            }                                                                 \
    };                                                                        \
    auto do_step = [&](int s, bool last, short8 (&bcur)[2][2],                \
                       short8 (&bnxt)[2][2]) {                                \
        const int b = s % 3;                                                  \
        if (last) asm volatile("s_waitcnt vmcnt(0)" ::: "memory");            \
        else      asm volatile("s_waitcnt vmcnt(2)" ::: "memory");            \
        __builtin_amdgcn_sched_barrier(0);                                    \
        __builtin_amdgcn_s_barrier();                                         \
        __builtin_amdgcn_sched_barrier(0);                                    \
        if (!last) loadB(s + 1, bnxt);                                        \
        if (s + 2 < 8) stage(s + 2);                                          \
        _Pragma("unroll")                                                     \
        for (int h = 0; h < 2; ++h) {                                         \
            _Pragma("unroll")                                                 \
            for (int i = 0; i < 8; ++i) {                                     \
                int r = i * 16 + l15;                                         \
                short8 a = *(const short8*)(SMEM + b * 16384 + r * 128        \
                                + (((lg + 4 * h) ^ (r & 7)) << 4));           \
                acc[i][0] = __builtin_amdgcn_mfma_f32_16x16x32_bf16(          \
                    a, bcur[h][0], acc[i][0], 0, 0, 0);                       \
                acc[i][1] = __builtin_amdgcn_mfma_f32_16x16x32_bf16(          \
                    a, bcur[h][1], acc[i][1], 0, 0, 0);                       \
            }                                                                 \
        }                                                                     \
    };                                                                        \
    short8 b0[2][2], b1r[2][2];                                               \
    loadB(0, b0);                                                             \
    stage(0);                                                                 \
    stage(1);                                                                 \
    do_step(0, false, b0, b1r);                                               \
    do_step(1, false, b1r, b0);                                               \
    do_step(2, false, b0, b1r);                                               \
    do_step(3, false, b1r, b0);                                               \
    do_step(4, false, b0, b1r);                                               \
    do_step(5, false, b1r, b0);                                               \
    do_step(6, false, b0, b1r);                                               \
    do_step(7, true,  b1r, b0);

// ---------------------------------------------------------------------------
// SAGE layers 1-2: Out = relu([Agg|X] @ Wt^T + bias)   (K=512)
// ---------------------------------------------------------------------------
__global__ __launch_bounds__(512, 4) void k_sage(
    const __hip_bfloat16* __restrict__ Agg,
    const __hip_bfloat16* __restrict__ X,
    const __hip_bfloat16* __restrict__ Wt,
    const float* __restrict__ bias,
    __hip_bfloat16* __restrict__ Out)
{
    __shared__ char smem[49152];
    SAGE_KLOOP(smem)

    __syncthreads();
    // Epilogue: two 64-row halves through LDS, coalesced 16B stores
    __hip_bfloat16* lo = (__hip_bfloat16*)smem;
    #pragma unroll
    for (int hh = 0; hh < 2; ++hh) {
        #pragma unroll
        for (int n = 0; n < 2; ++n) {
            int c = w * 32 + n * 16 + l15;
            float bv = bias[c];
            #pragma unroll
            for (int i2 = 0; i2 < 4; ++i2) {
                int i = hh * 4 + i2;
                #pragma unroll
                for (int r = 0; r < 4; ++r) {
                    int rl = i2 * 16 + lg * 4 + r;
                    lo[rl * 256 + c] = __float2bfloat16(fmaxf(acc[i][n][r] + bv, 0.0f));
                }
            }
        }
        __syncthreads();
        #pragma unroll
        for (int q = 0; q < 4; ++q) {
            int chunk = tid + q * 512;
            int rl = chunk >> 5, cc = chunk & 31;
            int grow = row0 + hh * 64 + rl;
            if (grow < N_NODES)
                *(uint4*)((char*)Out + (size_t)grow * 512 + cc * 16) =
                    *(const uint4*)((const char*)smem + rl * 512 + cc * 16);
        }
        __syncthreads();
    }
}

// ---------------------------------------------------------------------------
// SAGE layer 3 + head, fused.  x3 tile kept in LDS (never hits HBM):
//   x3 = relu([Agg|X] @ Wt^T + bl3)          (K-loop, as above)
//   h  = relu(x3 @ Wh^T + b0);  pred = h.W1 + b1
// Head GEMM reads A-frags from the swizzled LDS x3 tile (no staging, no
// barriers in that phase); W1-dot reduced over 16 lanes (shfl) then across
// 8 waves via a 4KB LDS partial array.  One fp32 store per row.
// ---------------------------------------------------------------------------
__global__ __launch_bounds__(512, 4) void k_sage3(
    const __hip_bfloat16* __restrict__ Agg,
    const __hip_bfloat16* __restrict__ X,
    const __hip_bfloat16* __restrict__ Wt,
    const float* __restrict__ bias,
    const __hip_bfloat16* __restrict__ Wh,
    const float* __restrict__ hb0,
    const float* __restrict__ W1,
    const float* __restrict__ b1,
    float* __restrict__ Pred)
{
    __shared__ char smem[65536];    // K-loop: 3x16KB staging; then 128x256 x3
    SAGE_KLOOP(smem)

    __syncthreads();
    // Write x3 tile (relu+bias) into LDS, XOR-swizzled 16B chunks so the
    // head GEMM's ds_read_b128 (16 lanes, stride-512B rows) is conflict-free.
    #pragma unroll
    for (int n = 0; n < 2; ++n) {
        int c = w * 32 + n * 16 + l15;
        float bv = bias[c];
        int chunk = c >> 3;
        int chi = chunk & 24, clo = chunk & 7;
        #pragma unroll
        for (int i = 0; i < 8; ++i)
            #pragma unroll
            for (int r = 0; r < 4; ++r) {
                int row = i * 16 + lg * 4 + r;
                __hip_bfloat16 hv = __float2bfloat16(fmaxf(acc[i][n][r] + bv, 0.0f));
                *(short*)(smem + row * 512 + (chi | (clo ^ (row & 7))) * 16
                          + (c & 7) * 2) = *(short*)&hv;
            }
    }
    __syncthreads();

    // Head GEMM: hacc = x3 @ Wh^T   (K=256; A from LDS, B from L2-hot Wh)
    f32x4 hacc[8][2];
    #pragma unroll
    for (int i = 0; i < 8; ++i)
        #pragma unroll
        for (int n = 0; n < 2; ++n) hacc[i][n] = (f32x4)0.0f;
    #pragma unroll
    for (int ks = 0; ks < 4; ++ks) {
        #pragma unroll
        for (int h = 0; h < 2; ++h) {
            short8 bb[2];
            #pragma unroll
            for (int n = 0; n < 2; ++n) {
                int c = w * 32 + n * 16 + l15;
                bb[n] = *(const short8*)(Wh + (size_t)c * 256 + ks * 64 + h * 32 + 8 * lg);
            }
            #pragma unroll
            for (int i = 0; i < 8; ++i) {
                int r = i * 16 + l15;
                int swz = ks * 8 + ((h * 4 + lg) ^ (r & 7));
                short8 a = *(const short8*)(smem + r * 512 + swz * 16);
                hacc[i][0] = __builtin_amdgcn_mfma_f32_16x16x32_bf16(a, bb[0], hacc[i][0], 0, 0, 0);
                hacc[i][1] = __builtin_amdgcn_mfma_f32_16x16x32_bf16(a, bb[1], hacc[i][1], 0, 0, 0);
            }
        }
    }
    __syncthreads();    // all head-GEMM LDS reads done before part overwrite

    // pred partials: relu(hacc+b0).W1 over this wave's 32 cols
    float* part = (float*)smem;     // [128][8]
    #pragma unroll
    for (int i = 0; i < 8; ++i) {
        float p[4];
        #pragma unroll
        for (int r = 0; r < 4; ++r) p[r] = 0.0f;
        #pragma unroll
        for (int n = 0; n < 2; ++n) {
            int cg = w * 32 + n * 16 + l15;
            float bv = hb0[cg];
            float wv = W1[cg];
            #pragma unroll
            for (int r = 0; r < 4; ++r)
                p[r] += fmaxf(hacc[i][n][r] + bv, 0.0f) * wv;
        }
        #pragma unroll
        for (int r = 0; r < 4; ++r) {
            float s = p[r];
            #pragma unroll
            for (int m = 1; m < 16; m <<= 1) s += __shfl_xor(s, m, 64);
            if (l15 == 0)
                part[(i * 16 + lg * 4 + r) * 8 + w] = s;
        }
    }
    __syncthreads();
    if (tid < 128) {
        int grow = row0 + tid;
        if (grow < N_NODES) {
            float s = b1[0];
            #pragma unroll
            for (int j = 0; j < 8; ++j) s += part[tid * 8 + j];
            Pred[grow] = s;
        }
    }
}

extern "C" void kernel_launch(void* const* d_in, const int* in_sizes, int n_in,
                              void* d_out, int out_size, void* d_ws, size_t ws_size,
                              hipStream_t stream) {
    const float* node_attr = (const float*)d_in[0];
    const float* y         = (const float*)d_in[1];
    const float* node_emb  = (const float*)d_in[2];
    const float* net_W     = (const float*)d_in[4];
    const float* net_b     = (const float*)d_in[5];
    const float* dev_W     = (const float*)d_in[6];
    const float* dev_b     = (const float*)d_in[7];
    const float* pin_emb   = (const float*)d_in[8];
    const float* sage_Wl   = (const float*)d_in[9];
    const float* sage_bl   = (const float*)d_in[10];
    const float* sage_Wr   = (const float*)d_in[11];
    const float* head_W0   = (const float*)d_in[12];
    const float* head_b0   = (const float*)d_in[13];
    const float* head_W1   = (const float*)d_in[14];
    const float* head_b1   = (const float*)d_in[15];
    const int*   node_type = (const int*)d_in[16];
    const int*   edge_idx  = (const int*)d_in[18];
    float* out = (float*)d_out;

    const size_t xelems = (size_t)N_NODES * HID;
    char* p = (char*)d_ws;
    __hip_bfloat16* x0  = (__hip_bfloat16*)p;  p += xelems * 2;
    __hip_bfloat16* x1  = (__hip_bfloat16*)p;  p += xelems * 2;
    __hip_bfloat16* agg = (__hip_bfloat16*)p;  p += xelems * 2;
    __hip_bfloat16* Wt  = (__hip_bfloat16*)p;  p += (size_t)3 * 256 * 512 * 2;
    __hip_bfloat16* Wh  = (__hip_bfloat16*)p;  p += (size_t)256 * 256 * 2;
    int* deg    = (int*)p; p += N_NODES * 4;
    int* off    = (int*)p; p += N_NODES * 4;
    int* cursor = (int*)p; p += N_NODES * 4;
    int* slots  = (int*)p; p += N_EDGES * 4;
    int* total  = (int*)p; p += 16;

    k_prep<<<(3 * 131072 + 65536 + 255) / 256, 256, 0, stream>>>(
        sage_Wl, sage_Wr, head_W0, Wt, Wh, deg, total);
    k_init<<<(N_NODES * 33 + N_EDGES + 255) / 256, 256, 0, stream>>>(
        node_attr, node_emb, net_W, net_b, dev_W, dev_b, pin_emb, node_type,
        y, head_b1, edge_idx, deg, out, x0);
    k_alloc<<<(N_NODES + 255) / 256, 256, 0, stream>>>(deg, off, cursor, total);
    k_fill<<<(N_EDGES + 255) / 256, 256, 0, stream>>>(edge_idx, cursor, slots);

    const int gemm_grid = (N_NODES + 127) / 128;
    // layer 1
    k_aggregate<<<(N_NODES / 4 * 64 + 255) / 256, 256, 0, stream>>>(
        x0, off, deg, slots, agg);
    k_sage<<<gemm_grid, 512, 0, stream>>>(
        agg, x0, Wt, sage_bl, x1);
    // layer 2
    k_aggregate<<<(N_NODES / 4 * 64 + 255) / 256, 256, 0, stream>>>(
        x1, off, deg, slots, agg);
    k_sage<<<gemm_grid, 512, 0, stream>>>(
        agg, x1, Wt + 131072, sage_bl + HID, x0);
    // layer 3 + head, fused
    k_aggregate<<<(N_NODES / 4 * 64 + 255) / 256, 256, 0, stream>>>(
        x0, off, deg, slots, agg);
    k_sage3<<<gemm_grid, 512, 0, stream>>>(
        agg, x0, Wt + 2 * 131072, sage_bl + 2 * HID,
        Wh, head_b0, head_W1, head_b1, out);
}